// Round 3
// baseline (321.828 us; speedup 1.0000x reference)
//
#include <hip/hip_runtime.h>

#define B_  4096
#define G_  31
#define GG_ 961      // G*G
#define P_  8
#define C_  36       // P*(P+1)/2
#define R_  4        // b-values per block

// One launch. Block = 256 threads = 4 waves; block owns R_=4 consecutive b's
// and sweeps all 961 gh cells in 4 passes of 256. Per pass each thread holds
// its cell's 36 coeffs in registers and the 4 b's 8 params (2 float4 each).
// t-form quadratic: q = sum_i p_i * (sum_{j>=i} c_ij p_j)  -> 44 FMA/cell.
// Reduction: wave butterfly -> 64B LDS -> exclusive store (no atomics/zeroing).
// VGPR budget: 36 cf + 32 param + ~20 misc ~= 90 -> no spill at (256,4).
__global__ __launch_bounds__(256, 4)
void quadform_kernel(const float* __restrict__ param,
                     const float* __restrict__ coef,
                     float* __restrict__ out) {
    const int tid  = threadIdx.x;
    const int lane = tid & 63;
    const int wv   = tid >> 6;                       // 4 waves/block
    const int b0   = blockIdx.x * R_;

    __shared__ float red[4][R_];

    float s[R_] = {0.0f, 0.0f, 0.0f, 0.0f};

    const float4* pb = reinterpret_cast<const float4*>(param);
    const float4* cb = reinterpret_cast<const float4*>(coef);
    const size_t bstep = (size_t)GG_ * 2;            // float4 units per b

    for (int pass = 0; pass < 4; ++pass) {           // 4*256 = 1024 >= 961
        const int  gh    = pass * 256 + tid;
        const bool valid = gh < GG_;
        const int  ghc   = valid ? gh : (GG_ - 1);   // clamp for safe addressing

        // ---- param loads first (HBM, longest latency): 8 x dwordx4 ----
        const size_t base = ((size_t)b0 * GG_ + ghc) * 2;
        float4 p[R_][2];
        #pragma unroll
        for (int r = 0; r < R_; ++r) {
            p[r][0] = pb[base + (size_t)r * bstep];
            p[r][1] = pb[base + (size_t)r * bstep + 1];
        }

        // ---- coeffs (L2-resident, 144B/cell): 9 x dwordx4 ----
        float cf[C_];
        {
            const float4* cp = cb + (size_t)ghc * (C_ / 4);
            #pragma unroll
            for (int q = 0; q < C_ / 4; ++q) {
                float4 v = cp[q];
                cf[4*q+0] = v.x; cf[4*q+1] = v.y; cf[4*q+2] = v.z; cf[4*q+3] = v.w;
            }
        }
        if (!valid) {
            #pragma unroll
            for (int c = 0; c < C_; ++c) cf[c] = 0.0f;
        }

        // ---- 4 independent t-form quadratic chains ----
        #pragma unroll
        for (int r = 0; r < R_; ++r) {
            const float pv[P_] = {p[r][0].x, p[r][0].y, p[r][0].z, p[r][0].w,
                                  p[r][1].x, p[r][1].y, p[r][1].z, p[r][1].w};
            float acc = 0.0f;
            int c = 0;
            #pragma unroll
            for (int i = 0; i < P_; ++i) {
                float t = 0.0f;
                #pragma unroll
                for (int j = i; j < P_; ++j) {       // np.triu_indices order
                    t = fmaf(cf[c], pv[j], t);
                    ++c;
                }
                acc = fmaf(pv[i], t, acc);
            }
            s[r] += acc;
        }
    }

    // ---- reduce: butterfly over 64 lanes (4 interleaved chains) ----
    #pragma unroll
    for (int off = 32; off; off >>= 1) {
        #pragma unroll
        for (int r = 0; r < R_; ++r) s[r] += __shfl_xor(s[r], off, 64);
    }
    if (lane == 0) {
        #pragma unroll
        for (int r = 0; r < R_; ++r) red[wv][r] = s[r];
    }
    __syncthreads();

    // ---- cross-wave: 4 values per b, exclusive store ----
    if (tid < R_) {
        out[b0 + tid] = red[0][tid] + red[1][tid] + red[2][tid] + red[3][tid];
    }
}

extern "C" void kernel_launch(void* const* d_in, const int* in_sizes, int n_in,
                              void* d_out, int out_size, void* d_ws, size_t ws_size,
                              hipStream_t stream) {
    const float* param = (const float*)d_in[0];   // [B, G, G, P] fp32
    const float* coef  = (const float*)d_in[1];   // [G, G, C]  fp32
    float* out = (float*)d_out;                   // [B] fp32

    quadform_kernel<<<B_ / R_, 256, 0, stream>>>(param, coef, out);  // 1024 blocks
}

// Round 4
// 185.251 us; speedup vs baseline: 1.7373x; 1.7373x over previous
//
#include <hip/hip_runtime.h>

#define B_  4096
#define G_  31
#define GG_ 961      // G*G
#define P_  8
#define C_  36       // P*(P+1)/2
#define R_  4        // b-values per block

// One launch. Block = 256 threads = 4 waves; block owns R_=4 consecutive b's
// and sweeps all 961 gh cells in 4 passes of 256 (param read once, coalesced:
// 64 lanes x 32B = 2KB contiguous per wave per b).
// Register-pressure-first design: coeffs consumed one float4 at a time so peak
// live state is ~55 floats (pv 32 + acc 4 + s 4 + c4 4 + addr). Round-3 showed
// the AMDGPU occupancy heuristic caps at 64 VGPR and spills whole arrays
// (WRITE_SIZE 284 MB of scratch) if live state exceeds it — never hold cf[36].
// Reduction: 64-lane butterfly -> 64B LDS -> exclusive store (no atomics).
__global__ __launch_bounds__(256)
void quadform_kernel(const float* __restrict__ param,
                     const float* __restrict__ coef,
                     float* __restrict__ out) {
    // np.triu_indices(8) pair order
    static const int II[C_] = {0,0,0,0,0,0,0,0, 1,1,1,1,1,1,1, 2,2,2,2,2,2,
                               3,3,3,3,3, 4,4,4,4, 5,5,5, 6,6, 7};
    static const int JJ[C_] = {0,1,2,3,4,5,6,7, 1,2,3,4,5,6,7, 2,3,4,5,6,7,
                               3,4,5,6,7, 4,5,6,7, 5,6,7, 6,7, 7};

    const int tid  = threadIdx.x;
    const int lane = tid & 63;
    const int wv   = tid >> 6;                       // 4 waves/block
    const int b0   = blockIdx.x * R_;

    __shared__ float red[4][R_];

    float s[R_] = {0.0f, 0.0f, 0.0f, 0.0f};

    const float4* pb = reinterpret_cast<const float4*>(param);
    const float4* cb = reinterpret_cast<const float4*>(coef);
    const size_t bstep = (size_t)GG_ * 2;            // float4 units per b

    for (int pass = 0; pass < 4; ++pass) {           // 4*256 = 1024 >= 961
        const int  gh    = pass * 256 + tid;
        const bool valid = gh < GG_;
        const int  ghc   = valid ? gh : (GG_ - 1);   // clamp for safe addressing

        // ---- param: 8 x dwordx4, issued up front (HBM latency) ----
        const size_t base = ((size_t)b0 * GG_ + ghc) * 2;
        float pv[R_][P_];
        #pragma unroll
        for (int r = 0; r < R_; ++r) {
            float4 a = pb[base + (size_t)r * bstep];
            float4 b = pb[base + (size_t)r * bstep + 1];
            pv[r][0] = a.x; pv[r][1] = a.y; pv[r][2] = a.z; pv[r][3] = a.w;
            pv[r][4] = b.x; pv[r][5] = b.y; pv[r][6] = b.z; pv[r][7] = b.w;
        }

        // ---- coeffs: stream 9 float4s, each consumed then dead ----
        const float4* cp = cb + (size_t)ghc * (C_ / 4);
        float acc[R_] = {0.0f, 0.0f, 0.0f, 0.0f};
        #pragma unroll
        for (int q = 0; q < C_ / 4; ++q) {
            const float4 c4 = cp[q];
            #pragma unroll
            for (int k = 0; k < 4; ++k) {
                const int   c  = 4 * q + k;
                const int   i  = II[c], j = JJ[c];
                const float cv = (k == 0) ? c4.x : (k == 1) ? c4.y
                               : (k == 2) ? c4.z : c4.w;
                #pragma unroll
                for (int r = 0; r < R_; ++r)
                    acc[r] = fmaf(cv * pv[r][i], pv[r][j], acc[r]);
            }
        }

        if (valid) {
            #pragma unroll
            for (int r = 0; r < R_; ++r) s[r] += acc[r];
        }
    }

    // ---- reduce: butterfly over 64 lanes (4 interleaved chains) ----
    #pragma unroll
    for (int off = 32; off; off >>= 1) {
        #pragma unroll
        for (int r = 0; r < R_; ++r) s[r] += __shfl_xor(s[r], off, 64);
    }
    if (lane == 0) {
        #pragma unroll
        for (int r = 0; r < R_; ++r) red[wv][r] = s[r];
    }
    __syncthreads();

    // ---- cross-wave: 4 partials per b, exclusive store ----
    if (tid < R_) {
        out[b0 + tid] = red[0][tid] + red[1][tid] + red[2][tid] + red[3][tid];
    }
}

extern "C" void kernel_launch(void* const* d_in, const int* in_sizes, int n_in,
                              void* d_out, int out_size, void* d_ws, size_t ws_size,
                              hipStream_t stream) {
    const float* param = (const float*)d_in[0];   // [B, G, G, P] fp32
    const float* coef  = (const float*)d_in[1];   // [G, G, C]  fp32
    float* out = (float*)d_out;                   // [B] fp32

    quadform_kernel<<<B_ / R_, 256, 0, stream>>>(param, coef, out);  // 1024 blocks
}